// Round 7
// baseline (144.756 us; speedup 1.0000x reference)
//
#include <hip/hip_runtime.h>

#define D 1024
#define T 2048
#define BATCH 4

typedef float nfloat4 __attribute__((ext_vector_type(4)));  // native vec for nontemporal builtin

// workspace float offsets
#define WS_PARTW 0        // [16][1024] : wbar partial sums (esub-major), 16 KB*4
#define WS_BBAR  16384    // 1 float    : mean(bk)
#define WS_Z     16388    // 4 floats   : Z[b] = sum_t exp(cos(kmean))
#define WS_CTR   16392    // 4 ints     : arrival counters per batch
#define WS_ZP    16640    // 1024       : per-block Z partials
#define WS_U     17664    // 4096       : u[b][d] = sum_t e_t*x[b,t,d] (16B aligned)
#define WS_O     21760    // 4096       : o[b][d]
#define WS_PART  32768    // [4][256][1024] : per-block u partials (4 MB)
#define WS_NEED  (((size_t)WS_PART + 1024 * 1024) * 4)

// ---- K1: wbar partials (256 blocks), bbar+zero Z/ctr (block 256), zero u (257)
__global__ void __launch_bounds__(256) k_prep(const float4* __restrict__ Wk4,
                                              const float* __restrict__ bk,
                                              float* __restrict__ ws) {
    __shared__ float4 sm[16][17];
    __shared__ float red[256];
    const int bid = blockIdx.x, tid = threadIdx.x;
    if (bid < 256) {
        const int esub = bid & 15, dchunk = bid >> 4;  // e-range 64, d4-range 16
        const int fc = tid & 15, eg = tid >> 4;
        const int d4 = dchunk * 16 + fc;
        float4 s = make_float4(0.f, 0.f, 0.f, 0.f);
        #pragma unroll
        for (int k = 0; k < 4; ++k) {
            const int e = esub * 64 + k * 16 + eg;
            const float4 v = Wk4[e * 256 + d4];
            s.x += v.x; s.y += v.y; s.z += v.z; s.w += v.w;
        }
        sm[eg][fc] = s;
        __syncthreads();
        if (tid < 16) {
            float4 t = make_float4(0.f, 0.f, 0.f, 0.f);
            #pragma unroll
            for (int g = 0; g < 16; ++g) {
                const float4 v = sm[g][tid];
                t.x += v.x; t.y += v.y; t.z += v.z; t.w += v.w;
            }
            ((float4*)(ws + WS_PARTW))[esub * 256 + dchunk * 16 + tid] = t;
        }
    } else if (bid == 256) {
        red[tid] = bk[tid] + bk[tid + 256] + bk[tid + 512] + bk[tid + 768];
        __syncthreads();
        for (int off = 128; off > 0; off >>= 1) {
            if (tid < off) red[tid] += red[tid + off];
            __syncthreads();
        }
        if (tid == 0) ws[WS_BBAR] = red[0] * (1.0f / D);
        if (tid < 4) ws[WS_Z + tid] = 0.f;
        if (tid >= 8 && tid < 12) ((int*)ws)[WS_CTR + tid - 8] = 0;
    } else {
        float4* u4 = (float4*)(ws + WS_U);
        #pragma unroll
        for (int k = 0; k < 4; ++k)
            u4[k * 256 + tid] = make_float4(0.f, 0.f, 0.f, 0.f);
    }
}

// ---- K2: single pass over x (batched 8 rows, one sync) + fused last-block
//          per-batch reduction of partials into u[b,:], Z[b].
template <bool USE_PART>
__global__ void __launch_bounds__(256) k_pass(const float4* __restrict__ x4,
                                              float* __restrict__ ws) {
    __shared__ float lds[4][8];
    __shared__ float zred[4];
    __shared__ int isLast;
    const int tid = threadIdx.x, lane = tid & 63, w = tid >> 6;
    const int bid = blockIdx.x;
    const int b = bid >> 8, tc = bid & 255;

    // wbar[tid] (float4) from the 16 e-subrange partials (L2-hot)
    const float4* pw = (const float4*)(ws + WS_PARTW);
    float4 wq = make_float4(0.f, 0.f, 0.f, 0.f);
    #pragma unroll
    for (int s = 0; s < 16; ++s) {
        const float4 v = pw[s * 256 + tid];
        wq.x += v.x; wq.y += v.y; wq.z += v.z; wq.w += v.w;
    }
    wq.x *= (1.0f / D); wq.y *= (1.0f / D);
    wq.z *= (1.0f / D); wq.w *= (1.0f / D);
    const float bbar = ws[WS_BBAR];

    // phase 1: load 8 rows (independent -> deep ILP), dot partials
    const float4* xr = x4 + (size_t)(b * T + tc * 8) * 256;
    float4 xv[8];
    #pragma unroll
    for (int j = 0; j < 8; ++j) xv[j] = xr[j * 256 + tid];
    float p[8];
    #pragma unroll
    for (int j = 0; j < 8; ++j)
        p[j] = xv[j].x * wq.x + xv[j].y * wq.y + xv[j].z * wq.z + xv[j].w * wq.w;

    // phase 2: batched block reduction, one sync
    #pragma unroll
    for (int off = 32; off > 0; off >>= 1) {
        #pragma unroll
        for (int j = 0; j < 8; ++j) p[j] += __shfl_down(p[j], off);
    }
    if (lane == 0) {
        #pragma unroll
        for (int j = 0; j < 8; ++j) lds[w][j] = p[j];
    }
    __syncthreads();

    float e[8];
    float zs = 0.f;
    #pragma unroll
    for (int j = 0; j < 8; ++j) {
        const float km = lds[0][j] + lds[1][j] + lds[2][j] + lds[3][j] + bbar;
        e[j] = expf(cosf(km));   // cos in [-1,1] -> exp in (0.36,2.72): no max needed
        zs += e[j];
    }
    float4 acc = make_float4(0.f, 0.f, 0.f, 0.f);
    #pragma unroll
    for (int j = 0; j < 8; ++j) {
        acc.x += e[j] * xv[j].x; acc.y += e[j] * xv[j].y;
        acc.z += e[j] * xv[j].z; acc.w += e[j] * xv[j].w;
    }

    if (USE_PART) {
        ((float4*)(ws + WS_PART))[(size_t)bid * 256 + tid] = acc;  // [b][tc][d4]
        if (tid == 0) ws[WS_ZP + bid] = zs;
        __threadfence();               // release: make this block's stores visible
        __syncthreads();               // all threads' fences done
        if (tid == 0) {
            const int t = atomicAdd((int*)ws + WS_CTR + b, 1);
            isLast = (t == 255);
        }
        __syncthreads();
        if (isLast) {                  // block-uniform: whole block participates
            __threadfence();           // acquire: see other XCDs' partials
            const float4* pb = (const float4*)(ws + WS_PART) + (size_t)b * 65536;
            float4 s = make_float4(0.f, 0.f, 0.f, 0.f);
            #pragma unroll 16
            for (int q = 0; q < 256; ++q) {
                const float4 v = pb[q * 256 + tid];
                s.x += v.x; s.y += v.y; s.z += v.z; s.w += v.w;
            }
            ((float4*)(ws + WS_U))[b * 256 + tid] = s;
            float z = ws[WS_ZP + b * 256 + tid];
            #pragma unroll
            for (int off = 32; off > 0; off >>= 1) z += __shfl_down(z, off);
            if (lane == 0) zred[w] = z;
            __syncthreads();
            if (tid == 0) ws[WS_Z + b] = zred[0] + zred[1] + zred[2] + zred[3];
        }
    } else {
        float* dst = ws + WS_U + b * D + tid * 4;
        atomicAdd(dst + 0, acc.x);
        atomicAdd(dst + 1, acc.y);
        atomicAdd(dst + 2, acc.z);
        atomicAdd(dst + 3, acc.w);
        if (tid == 0) atomicAdd(ws + WS_Z + b, zs);
    }
}

// ---- K3: o[b,d] = (u[b,:].Wv[d,:]) / Z[b] + bv[d] ; one block per d
__global__ void __launch_bounds__(256) k_proj(const float4* __restrict__ Wv4,
                                              float* __restrict__ ws,
                                              const float* __restrict__ bv) {
    __shared__ float lds[4][4];
    const int tid = threadIdx.x, lane = tid & 63, w = tid >> 6;
    const int d = blockIdx.x;
    const float4 wvv = Wv4[d * 256 + tid];
    const float4* u4 = (const float4*)(ws + WS_U);
    float a[BATCH];
    #pragma unroll
    for (int b = 0; b < BATCH; ++b) {
        const float4 u = u4[b * 256 + tid];
        a[b] = wvv.x * u.x + wvv.y * u.y + wvv.z * u.z + wvv.w * u.w;
    }
    #pragma unroll
    for (int off = 32; off > 0; off >>= 1) {
        #pragma unroll
        for (int b = 0; b < BATCH; ++b) a[b] += __shfl_down(a[b], off);
    }
    if (lane == 0) {
        #pragma unroll
        for (int b = 0; b < BATCH; ++b) lds[w][b] = a[b];
    }
    __syncthreads();
    if (tid == 0) {
        const float bb = bv[d];
        #pragma unroll
        for (int b = 0; b < BATCH; ++b) {
            const float s = lds[0][b] + lds[1][b] + lds[2][b] + lds[3][b];
            ws[WS_O + b * D + d] = s / ws[WS_Z + b] + bb;
        }
    }
}

// ---- K4: out[b,t,d] = o[b,d]  (32 MiB streaming broadcast write)
__global__ void __launch_bounds__(256) k_bcast(const float* __restrict__ ws,
                                               nfloat4* __restrict__ out4) {
    const nfloat4* o4 = (const nfloat4*)(ws + WS_O);
    const int idx = blockIdx.x * 256 + threadIdx.x;   // 0..1048575
    #pragma unroll
    for (int i = 0; i < 2; ++i) {
        const int f = idx + i * 1048576;              // 2^21 float4 total
        const nfloat4 v = o4[((f >> 19) << 8) + (f & 255)];
        __builtin_nontemporal_store(v, &out4[f]);
    }
}

extern "C" void kernel_launch(void* const* d_in, const int* in_sizes, int n_in,
                              void* d_out, int out_size, void* d_ws, size_t ws_size,
                              hipStream_t stream) {
    const float* x  = (const float*)d_in[0];
    // d_in[1] = Wq, d_in[2] = bq : dead code in the reference
    const float* Wk = (const float*)d_in[3];
    const float* bk = (const float*)d_in[4];
    const float* Wv = (const float*)d_in[5];
    const float* bv = (const float*)d_in[6];
    float* ws  = (float*)d_ws;
    float* out = (float*)d_out;

    const bool use_part = ws_size >= WS_NEED;

    k_prep<<<258, 256, 0, stream>>>((const float4*)Wk, bk, ws);
    if (use_part)
        k_pass<true><<<1024, 256, 0, stream>>>((const float4*)x, ws);
    else
        k_pass<false><<<1024, 256, 0, stream>>>((const float4*)x, ws);
    k_proj<<<1024, 256, 0, stream>>>((const float4*)Wv, ws, bv);
    k_bcast<<<4096, 256, 0, stream>>>(ws, (nfloat4*)out);
}

// Round 10
// 33.278 us; speedup vs baseline: 4.3499x; 4.3499x over previous
//
#include <hip/hip_runtime.h>

#define D 1024
#define T 2048
#define BATCH 4

typedef float nfloat4 __attribute__((ext_vector_type(4)));  // native vec for nontemporal builtin

// workspace float offsets
#define WS_WBAR  0        // 1024 : mean_e Wk[e,d]
#define WS_BBAR  1024     // 1    : mean(bk)
#define WS_Z     1028     // 4    : Z[b] = sum_t exp(cos(kmean))
#define WS_ZP    1088     // 512  : per-block Z partials
#define WS_U     1664     // 4096 : u[b][d] = sum_t e_t*x[b,t,d] (16B aligned)
#define WS_O     5760     // 4096 : o[b][d] (16B aligned)
#define WS_PART  16384    // [4][128][1024] : per-block u partials (2 MB)
#define WS_NEED  (((size_t)WS_PART + 4 * 128 * 1024) * 4)

// ---- K1: wbar direct (blocks 0..15: 16 float4-cols each), bbar+zero Z (16), zero u (17)
__global__ void __launch_bounds__(256) k_prep(const float4* __restrict__ Wk4,
                                              const float* __restrict__ bk,
                                              float* __restrict__ ws) {
    __shared__ float4 sm[16][17];
    __shared__ float red[256];
    const int bid = blockIdx.x, tid = threadIdx.x;
    if (bid < 16) {
        const int fc = tid & 15, eg = tid >> 4;      // 16 d4-cols x 16 e-groups
        const int d4 = bid * 16 + fc;                // 0..255  (D/4 = 256 cols)
        float4 s = make_float4(0.f, 0.f, 0.f, 0.f);
        #pragma unroll 8
        for (int k = 0; k < 64; ++k) {               // e = eg + 16*k : 0..1023
            const float4 v = Wk4[(eg + k * 16) * 256 + d4];
            s.x += v.x; s.y += v.y; s.z += v.z; s.w += v.w;
        }
        sm[eg][fc] = s;
        __syncthreads();
        if (tid < 16) {
            float4 t = make_float4(0.f, 0.f, 0.f, 0.f);
            #pragma unroll
            for (int g = 0; g < 16; ++g) {
                const float4 v = sm[g][tid];
                t.x += v.x; t.y += v.y; t.z += v.z; t.w += v.w;
            }
            t.x *= (1.0f / D); t.y *= (1.0f / D);
            t.z *= (1.0f / D); t.w *= (1.0f / D);
            ((float4*)(ws + WS_WBAR))[bid * 16 + tid] = t;   // 0..255 float4 ✓
        }
    } else if (bid == 16) {
        red[tid] = bk[tid] + bk[tid + 256] + bk[tid + 512] + bk[tid + 768];
        __syncthreads();
        for (int off = 128; off > 0; off >>= 1) {
            if (tid < off) red[tid] += red[tid + off];
            __syncthreads();
        }
        if (tid == 0) ws[WS_BBAR] = red[0] * (1.0f / D);
        if (tid < 4) ws[WS_Z + tid] = 0.f;
    } else {
        float4* u4 = (float4*)(ws + WS_U);
        #pragma unroll
        for (int k = 0; k < 4; ++k)
            u4[k * 256 + tid] = make_float4(0.f, 0.f, 0.f, 0.f);
    }
}

// ---- K2: single pass over x. 512 blocks x 16 rows (two 8-row halves).
// Per half: 8 independent row loads -> batched block-dot -> e=exp(cos) -> acc.
// Writes one u-partial (4 KB) + one Z-partial per block. No fences, no atomics.
template <bool USE_PART>
__global__ void __launch_bounds__(256) k_pass(const float4* __restrict__ x4,
                                              float* __restrict__ ws) {
    __shared__ float lds[2][4][8];
    const int tid = threadIdx.x, lane = tid & 63, w = tid >> 6;
    const int bid = blockIdx.x;
    const int b = bid >> 7, tc = bid & 127;          // 128 blocks/batch, 16 rows each

    const float4 wq = ((const float4*)(ws + WS_WBAR))[tid];
    const float bbar = ws[WS_BBAR];

    const float4* xr = x4 + (size_t)(b * T + tc * 16) * 256;
    float4 acc = make_float4(0.f, 0.f, 0.f, 0.f);
    float zs = 0.f;

    #pragma unroll
    for (int h = 0; h < 2; ++h) {
        float4 xv[8];
        #pragma unroll
        for (int j = 0; j < 8; ++j) xv[j] = xr[(h * 8 + j) * 256 + tid];
        float p[8];
        #pragma unroll
        for (int j = 0; j < 8; ++j)
            p[j] = xv[j].x * wq.x + xv[j].y * wq.y + xv[j].z * wq.z + xv[j].w * wq.w;
        #pragma unroll
        for (int off = 32; off > 0; off >>= 1) {
            #pragma unroll
            for (int j = 0; j < 8; ++j) p[j] += __shfl_down(p[j], off);
        }
        if (lane == 0) {
            #pragma unroll
            for (int j = 0; j < 8; ++j) lds[h][w][j] = p[j];
        }
        __syncthreads();
        #pragma unroll
        for (int j = 0; j < 8; ++j) {
            const float km = lds[h][0][j] + lds[h][1][j] + lds[h][2][j] + lds[h][3][j] + bbar;
            const float e = expf(cosf(km));  // cos in [-1,1] -> exp in (0.36,2.72)
            zs += e;
            acc.x += e * xv[j].x; acc.y += e * xv[j].y;
            acc.z += e * xv[j].z; acc.w += e * xv[j].w;
        }
    }

    if (USE_PART) {
        ((float4*)(ws + WS_PART))[(size_t)bid * 256 + tid] = acc;  // [b][tc][d4]
        if (tid == 0) ws[WS_ZP + bid] = zs;
    } else {
        float* dst = ws + WS_U + b * D + tid * 4;
        atomicAdd(dst + 0, acc.x);
        atomicAdd(dst + 1, acc.y);
        atomicAdd(dst + 2, acc.z);
        atomicAdd(dst + 3, acc.w);
        if (tid == 0) atomicAdd(ws + WS_Z + b, zs);
    }
}

// ---- K3: u[b][:] = sum over 128 partials (deterministic), Z[b] = sum ZP
__global__ void __launch_bounds__(256) k_reduce(float* __restrict__ ws) {
    __shared__ float4 sm[16][17];
    const int bid = blockIdx.x, tid = threadIdx.x;
    const int b = bid >> 4, dc = bid & 15;           // 16 blocks per batch
    const int dl = tid & 15, pg = tid >> 4;
    const float4* pb = (const float4*)(ws + WS_PART) + (size_t)b * 128 * 256;
    float4 s = make_float4(0.f, 0.f, 0.f, 0.f);
    #pragma unroll
    for (int k = 0; k < 8; ++k) {
        const float4 v = pb[(pg * 8 + k) * 256 + dc * 16 + dl];
        s.x += v.x; s.y += v.y; s.z += v.z; s.w += v.w;
    }
    sm[pg][dl] = s;
    __syncthreads();
    if (tid < 16) {
        float4 t = make_float4(0.f, 0.f, 0.f, 0.f);
        #pragma unroll
        for (int g = 0; g < 16; ++g) {
            const float4 v = sm[g][tid];
            t.x += v.x; t.y += v.y; t.z += v.z; t.w += v.w;
        }
        ((float4*)(ws + WS_U))[b * 256 + dc * 16 + tid] = t;
    }
    // Z-reduction: single wave, no barrier (divergent __syncthreads is UB -> hang)
    if (dc == 0 && tid < 64) {
        float z = ws[WS_ZP + b * 128 + tid] + ws[WS_ZP + b * 128 + 64 + tid];
        #pragma unroll
        for (int off = 32; off > 0; off >>= 1) z += __shfl_down(z, off);
        if (tid == 0) ws[WS_Z + b] = z;
    }
}

// ---- K4: o[b,d] = (u[b,:].Wv[d,:]) / Z[b] + bv[d] ; one block per d
__global__ void __launch_bounds__(256) k_proj(const float4* __restrict__ Wv4,
                                              float* __restrict__ ws,
                                              const float* __restrict__ bv) {
    __shared__ float lds[4][4];
    const int tid = threadIdx.x, lane = tid & 63, w = tid >> 6;
    const int d = blockIdx.x;
    const float4 wvv = Wv4[d * 256 + tid];
    const float4* u4 = (const float4*)(ws + WS_U);
    float a[BATCH];
    #pragma unroll
    for (int b = 0; b < BATCH; ++b) {
        const float4 u = u4[b * 256 + tid];
        a[b] = wvv.x * u.x + wvv.y * u.y + wvv.z * u.z + wvv.w * u.w;
    }
    #pragma unroll
    for (int off = 32; off > 0; off >>= 1) {
        #pragma unroll
        for (int b = 0; b < BATCH; ++b) a[b] += __shfl_down(a[b], off);
    }
    if (lane == 0) {
        #pragma unroll
        for (int b = 0; b < BATCH; ++b) lds[w][b] = a[b];
    }
    __syncthreads();
    if (tid == 0) {
        const float bb = bv[d];
        #pragma unroll
        for (int b = 0; b < BATCH; ++b) {
            const float s = lds[0][b] + lds[1][b] + lds[2][b] + lds[3][b];
            ws[WS_O + b * D + d] = s / ws[WS_Z + b] + bb;
        }
    }
}

// ---- K5: out[b,t,d] = o[b,d]  (32 MiB streaming broadcast write)
__global__ void __launch_bounds__(256) k_bcast(const float* __restrict__ ws,
                                               nfloat4* __restrict__ out4) {
    const nfloat4* o4 = (const nfloat4*)(ws + WS_O);
    const int idx = blockIdx.x * 256 + threadIdx.x;   // 0..1048575
    #pragma unroll
    for (int i = 0; i < 2; ++i) {
        const int f = idx + i * 1048576;              // 2^21 float4 total
        const nfloat4 v = o4[((f >> 19) << 8) + (f & 255)];
        __builtin_nontemporal_store(v, &out4[f]);
    }
}

extern "C" void kernel_launch(void* const* d_in, const int* in_sizes, int n_in,
                              void* d_out, int out_size, void* d_ws, size_t ws_size,
                              hipStream_t stream) {
    const float* x  = (const float*)d_in[0];
    // d_in[1] = Wq, d_in[2] = bq : dead code in the reference
    const float* Wk = (const float*)d_in[3];
    const float* bk = (const float*)d_in[4];
    const float* Wv = (const float*)d_in[5];
    const float* bv = (const float*)d_in[6];
    float* ws  = (float*)d_ws;
    float* out = (float*)d_out;

    const bool use_part = ws_size >= WS_NEED;

    k_prep<<<18, 256, 0, stream>>>((const float4*)Wk, bk, ws);
    if (use_part) {
        k_pass<true><<<512, 256, 0, stream>>>((const float4*)x, ws);
        k_reduce<<<64, 256, 0, stream>>>(ws);
    } else {
        k_pass<false><<<512, 256, 0, stream>>>((const float4*)x, ws);
    }
    k_proj<<<1024, 256, 0, stream>>>((const float4*)Wv, ws, bv);
    k_bcast<<<4096, 256, 0, stream>>>(ws, (nfloat4*)out);
}